// Round 15
// baseline (318.960 us; speedup 1.0000x reference)
//
#include <hip/hip_runtime.h>
#include <hip/hip_fp16.h>
#include <math.h>

#define FIN 35
#define F1  64
#define BSZ 512          // nodes per coarse bucket
#define BSH 9            // log2(BSZ)
#define SSH 17           // src bits in record (n <= 131072)
#define SMSK 0x1FFFF
#define GSH 7            // log2(g1 row bytes) = log2(64 feats * 2B)
#define MAXNB 256        // max buckets (n <= 131072)
#define PCH 8192         // edges per hist/place chunk => NCHUNK <= 512 for E <= 4.19M
#define SCAP 24576       // max bucket size for k_sort inv16 path (avg ~16.4K, max ~17K)

// ---------- phase 1: per-chunk histogram of coarse buckets ----------
__global__ void k_hist(const int* __restrict__ dst, int* __restrict__ cmat,
                       int E, int NB, int NCHUNK) {
    __shared__ int h[MAXNB];
    int c = blockIdx.x, t = threadIdx.x;
    for (int i = t; i < NB; i += 256) h[i] = 0;
    __syncthreads();
    int e0 = c * PCH, e1 = min(e0 + PCH, E);
    bool al = ((size_t)(dst + e0) & 15) == 0;
    int nv = al ? ((e1 - e0) >> 2) : 0;
    const int4* d4 = (const int4*)(dst + e0);
    for (int i = t; i < nv; i += 256) {
        int4 v = d4[i];
        atomicAdd(&h[v.x >> BSH], 1); atomicAdd(&h[v.y >> BSH], 1);
        atomicAdd(&h[v.z >> BSH], 1); atomicAdd(&h[v.w >> BSH], 1);
    }
    for (int e = e0 + (nv << 2) + t; e < e1; e += 256) atomicAdd(&h[dst[e] >> BSH], 1);
    __syncthreads();
    for (int i = t; i < NB; i += 256) cmat[(size_t)i * NCHUNK + c] = h[i];  // b-major
}

// ---------- phase 2a: row-local exclusive scan (one block per bucket row; NCHUNK <= 512) ----------
__global__ void k_scan_row(int* __restrict__ cmat, int* __restrict__ rsum, int NCHUNK) {
    __shared__ int s[512];
    int b = blockIdx.x, t = threadIdx.x;
    int v = (t < NCHUNK) ? cmat[(size_t)b * NCHUNK + t] : 0;
    s[t] = v;
    __syncthreads();
    #pragma unroll
    for (int off = 1; off < 512; off <<= 1) {
        int tv = (t >= off) ? s[t - off] : 0;
        __syncthreads();
        s[t] += tv;
        __syncthreads();
    }
    if (t < NCHUNK) cmat[(size_t)b * NCHUNK + t] = s[t] - v;   // row-local exclusive
    if (t == 511) rsum[b] = s[511];                            // row total
}

// ---------- phase 2b: exclusive scan of row totals -> bucket bases + boff (NB <= 1024) ----------
__global__ void k_scan_buck(const int* __restrict__ rsum, int* __restrict__ bbase,
                            int* __restrict__ boff, int NB, int E) {
    __shared__ int s[1024];
    int t = threadIdx.x;
    int v = (t < NB) ? rsum[t] : 0;
    s[t] = v;
    __syncthreads();
    #pragma unroll
    for (int off = 1; off < 1024; off <<= 1) {
        int tv = (t >= off) ? s[t - off] : 0;
        __syncthreads();
        s[t] += tv;
        __syncthreads();
    }
    if (t < NB) {
        int excl = s[t] - v;
        bbase[t] = excl;
        boff[t] = excl;
    }
    if (t == 0) boff[NB] = E;
}

// ---------- phase 3: placement — chunk-local LDS counting sort -> coalesced output ----------
// Records: rec.x = (dst_local << 17) | src. Bucket-major runs avg 42 contiguous
// records per (chunk,bucket) -> ~2-3 store transactions per wave. No device atomics.
__global__ __launch_bounds__(512) void k_place(
        const int* __restrict__ src, const int* __restrict__ dst,
        const float* __restrict__ ew, const int* __restrict__ cmat,
        const int* __restrict__ bbase,
        int2* __restrict__ recs, int E, int NB, int NCHUNK) {
    extern __shared__ char pmem[];
    int2* lrec   = (int2*)pmem;              // PCH records (64 KB)
    int*  addr32 = (int*)(lrec + PCH);       // PCH global addresses (32 KB)
    __shared__ int s[MAXNB];                 // counts -> inclusive scan
    __shared__ int lbase[MAXNB];             // chunk-local bucket base
    __shared__ int cur[MAXNB];               // chunk-local cursor
    __shared__ int gwin[MAXNB];              // global window base per bucket
    int c = blockIdx.x, t = threadIdx.x;
    if (t < MAXNB) s[t] = 0;
    __syncthreads();
    int e0 = c * PCH, e1 = min(e0 + PCH, E);
    bool al = (((size_t)(dst + e0) | (size_t)(src + e0) | (size_t)(ew + e0)) & 15) == 0;
    int nv = al ? ((e1 - e0) >> 2) : 0;
    const int4*   s4 = (const int4*)(src + e0);
    const int4*   d4 = (const int4*)(dst + e0);
    const float4* w4 = (const float4*)(ew + e0);
    // pass A: count
    for (int i = t; i < nv; i += 512) {
        int4 v = d4[i];
        atomicAdd(&s[v.x >> BSH], 1); atomicAdd(&s[v.y >> BSH], 1);
        atomicAdd(&s[v.z >> BSH], 1); atomicAdd(&s[v.w >> BSH], 1);
    }
    for (int e = e0 + (nv << 2) + t; e < e1; e += 512) atomicAdd(&s[dst[e] >> BSH], 1);
    __syncthreads();
    int v = (t < MAXNB) ? s[t] : 0;
    __syncthreads();
    #pragma unroll
    for (int off = 1; off < MAXNB; off <<= 1) {
        int tv = 0;
        if (t < MAXNB && t >= off) tv = s[t - off];
        __syncthreads();
        if (t < MAXNB) s[t] += tv;
        __syncthreads();
    }
    if (t < MAXNB) {
        lbase[t] = s[t] - v;
        cur[t] = 0;
        gwin[t] = (t < NB) ? (cmat[(size_t)t * NCHUNK + c] + bbase[t]) : 0;
    }
    __syncthreads();
    // pass B: scatter into LDS (record + final global address)
    for (int i = t; i < nv; i += 512) {
        int4   sv = s4[i];
        int4   dv = d4[i];
        float4 wv = w4[i];
        int b, r, sl;
        b = dv.x >> BSH; r = atomicAdd(&cur[b], 1); sl = lbase[b] + r;
        lrec[sl] = make_int2(sv.x | ((dv.x & (BSZ-1)) << SSH), __float_as_int(wv.x));
        addr32[sl] = gwin[b] + r;
        b = dv.y >> BSH; r = atomicAdd(&cur[b], 1); sl = lbase[b] + r;
        lrec[sl] = make_int2(sv.y | ((dv.y & (BSZ-1)) << SSH), __float_as_int(wv.y));
        addr32[sl] = gwin[b] + r;
        b = dv.z >> BSH; r = atomicAdd(&cur[b], 1); sl = lbase[b] + r;
        lrec[sl] = make_int2(sv.z | ((dv.z & (BSZ-1)) << SSH), __float_as_int(wv.z));
        addr32[sl] = gwin[b] + r;
        b = dv.w >> BSH; r = atomicAdd(&cur[b], 1); sl = lbase[b] + r;
        lrec[sl] = make_int2(sv.w | ((dv.w & (BSZ-1)) << SSH), __float_as_int(wv.w));
        addr32[sl] = gwin[b] + r;
    }
    for (int e = e0 + (nv << 2) + t; e < e1; e += 512) {
        int d = dst[e];
        int b = d >> BSH;
        int r = atomicAdd(&cur[b], 1);
        int sl = lbase[b] + r;
        lrec[sl] = make_int2(src[e] | ((d & (BSZ-1)) << SSH), __float_as_int(ew[e]));
        addr32[sl] = gwin[b] + r;
    }
    __syncthreads();
    // pass C: linear LDS walk -> coalesced bucket-major global stores
    int cnt = e1 - e0;
    for (int i = t; i < cnt; i += 512) recs[addr32[i]] = lrec[i];
}

// ---------- per-bucket counting sort via inverse permutation ----------
// NB = 196 blocks < 256 CUs -> single occupancy round, no tail. LDS: inv16
// (48 KB). recs_in read twice (2nd hits L2: window ~131KB); pass 3 random
// reads within L2-resident window, coalesced stores. Records out carry src<<7.
__global__ __launch_bounds__(1024) void k_sort(
        const int* __restrict__ boff, const int2* __restrict__ recs_in,
        int2* __restrict__ recs_out, int* __restrict__ row_ptr,
        float* __restrict__ dinv, int n) {
    extern __shared__ unsigned short inv16[];   // SCAP entries (48 KB)
    __shared__ int   hcnt[BSZ];
    __shared__ int   hoff[BSZ];
    __shared__ float dsum[BSZ];
    int b = blockIdx.x, t = threadIdx.x;
    if (t < BSZ) { hcnt[t] = 0; dsum[t] = 1.0f; }   // self-loop weight
    __syncthreads();
    int s0 = boff[b], s1 = boff[b + 1];
    int cnt = s1 - s0;
    // pass 1: histogram + weighted degree (coalesced global read)
    for (int i = t; i < cnt; i += 1024) {
        int2 rc = recs_in[s0 + i];
        int dl = ((unsigned)rc.x) >> SSH;
        atomicAdd(&hcnt[dl], 1);
        atomicAdd(&dsum[dl], __int_as_float(rc.y));
    }
    __syncthreads();
    int v = 0;
    if (t < BSZ) { v = hcnt[t]; hoff[t] = v; }
    __syncthreads();
    #pragma unroll
    for (int off = 1; off < BSZ; off <<= 1) {
        int tv = 0;
        if (t < BSZ && t >= off) tv = hoff[t - off];
        __syncthreads();
        if (t < BSZ) hoff[t] += tv;
        __syncthreads();
    }
    if (t < BSZ) {
        int excl = hoff[t] - v;
        int node = b * BSZ + t;
        if (node < n) {
            row_ptr[node] = s0 + excl;
            dinv[node] = rsqrtf(dsum[t]);
            if (node == n - 1) row_ptr[n] = s1;
        }
        hcnt[t] = excl;           // reuse as local cursor
    }
    __syncthreads();
    if (cnt <= SCAP) {
        // pass 2: positions -> inverse index (cnt <= SCAP < 65536 fits u16)
        for (int i = t; i < cnt; i += 1024) {
            int2 rc = recs_in[s0 + i];
            int dl = ((unsigned)rc.x) >> SSH;
            int pos = atomicAdd(&hcnt[dl], 1);
            inv16[pos] = (unsigned short)i;
        }
        __syncthreads();
        // pass 3: linear positions -> coalesced stores
        for (int o = t; o < cnt; o += 1024) {
            int2 rc = recs_in[s0 + inv16[o]];
            recs_out[s0 + o] = make_int2((rc.x & SMSK) << GSH, rc.y);
        }
    } else {
        // fallback (bucket larger than SCAP — not expected): direct scatter
        for (int i = t; i < cnt; i += 1024) {
            int2 rc = recs_in[s0 + i];
            int dl = ((unsigned)rc.x) >> SSH;
            int pos = atomicAdd(&hcnt[dl], 1);
            recs_out[s0 + pos] = make_int2((rc.x & SMSK) << GSH, rc.y);
        }
    }
}

// ---------- layer 1 GEMM: 64 rows/block; g1[row,f] = fp16(dinv*x@W1) ----------
__global__ void k_gemm1(const float* __restrict__ x, const float* __restrict__ W1,
                        const float* __restrict__ dinv, __half* __restrict__ g1, int n) {
    __shared__ float W1s[FIN * F1];    // 8960 B
    __shared__ float xs[64 * FIN];     // 8960 B
    int t = threadIdx.x;
    for (int i = t; i < FIN * F1; i += 256) W1s[i] = W1[i];
    int row0 = blockIdx.x * 64;
    int nrows = min(64, n - row0);
    for (int i = t; i < nrows * FIN; i += 256) xs[i] = x[(size_t)row0 * FIN + i];
    __syncthreads();
    int wave = t >> 6, f = t & 63;
    for (int rl = wave; rl < nrows; rl += 4) {
        float acc = 0.0f;
        #pragma unroll
        for (int k = 0; k < FIN; k++) acc += xs[rl * FIN + k] * W1s[k * F1 + f];
        int row = row0 + rl;
        g1[(size_t)row * F1 + f] = __float2half(acc * dinv[row]);
    }
}

// ---------- fused: layer-1 gather (fp16 rows, 16-way MLP, prescaled offsets)
// ---------- + ReLU + layer-2 GEMM (64->2) ----------
__global__ void k_gather1(const int* __restrict__ rp, const int2* __restrict__ csr,
                          const __half* __restrict__ g1,
                          const float* __restrict__ dinv, const float* __restrict__ b1,
                          const float* __restrict__ W2, float* __restrict__ g2, int n) {
    int wid = (int)((blockIdx.x * (long long)blockDim.x + threadIdx.x) >> 6);
    int f = threadIdx.x & 63;
    if (wid >= n) return;
    const char* g1b = (const char*)g1 + f * 2;   // lane's feature column
    int start = rp[wid], end = rp[wid + 1];
    float acc = 0.0f;
    int e = start;
    for (; e + 16 <= end; e += 16) {           // 16 row-gathers in flight
        float a[16];
        int2 r[16];
        #pragma unroll
        for (int j = 0; j < 16; j++) r[j] = csr[e + j];
        #pragma unroll
        for (int j = 0; j < 16; j++)
            a[j] = __half2float(*(const __half*)(g1b + (unsigned)r[j].x));
        #pragma unroll
        for (int j = 0; j < 16; j++) acc += __int_as_float(r[j].y) * a[j];
    }
    for (; e + 4 <= end; e += 4) {
        int2 r0 = csr[e], r1 = csr[e+1], r2 = csr[e+2], r3 = csr[e+3];
        float a0 = __half2float(*(const __half*)(g1b + (unsigned)r0.x));
        float a1 = __half2float(*(const __half*)(g1b + (unsigned)r1.x));
        float a2 = __half2float(*(const __half*)(g1b + (unsigned)r2.x));
        float a3 = __half2float(*(const __half*)(g1b + (unsigned)r3.x));
        acc += __int_as_float(r0.y) * a0; acc += __int_as_float(r1.y) * a1;
        acc += __int_as_float(r2.y) * a2; acc += __int_as_float(r3.y) * a3;
    }
    for (; e < end; e++) {
        int2 r = csr[e];
        acc += __int_as_float(r.y) * __half2float(*(const __half*)(g1b + (unsigned)r.x));
    }
    float dv = dinv[wid];
    float h = dv * (acc + __half2float(g1[(size_t)wid * F1 + f])) + b1[f]; // self-loop w=1
    h = h > 0.0f ? h : 0.0f;
    float2 w2v = ((const float2*)W2)[f];
    float z0 = h * w2v.x, z1 = h * w2v.y;
    #pragma unroll
    for (int off = 32; off > 0; off >>= 1) {
        z0 += __shfl_xor(z0, off, 64);
        z1 += __shfl_xor(z1, off, 64);
    }
    if (f == 0) {
        g2[(size_t)wid * 2 + 0] = dv * z0;
        g2[(size_t)wid * 2 + 1] = dv * z1;
    }
}

// ---------- fused: layer-2 gather (4-way MLP, prescaled offsets) + bias + log_softmax ----------
__global__ void k_gather2(const int* __restrict__ rp, const int2* __restrict__ csr,
                          const float* __restrict__ g2,
                          const float* __restrict__ dinv, const float* __restrict__ b2,
                          float* __restrict__ out, int n) {
    int wid = (int)((blockIdx.x * (long long)blockDim.x + threadIdx.x) >> 6);
    int lane = threadIdx.x & 63;
    if (wid >= n) return;
    const char* g2b = (const char*)g2;
    int start = rp[wid], end = rp[wid + 1];
    float a0 = 0.0f, a1 = 0.0f;
    int e = start + lane;
    for (; e + 192 < end; e += 256) {          // 4 gathers in flight
        int2 q0 = csr[e], q1 = csr[e + 64], q2 = csr[e + 128], q3 = csr[e + 192];
        // rec.x = src*128; g2 float2 byte offset = src*8 = rec.x>>4
        float2 v0 = *(const float2*)(g2b + (((unsigned)q0.x) >> 4));
        float2 v1 = *(const float2*)(g2b + (((unsigned)q1.x) >> 4));
        float2 v2 = *(const float2*)(g2b + (((unsigned)q2.x) >> 4));
        float2 v3 = *(const float2*)(g2b + (((unsigned)q3.x) >> 4));
        a0 += __int_as_float(q0.y) * v0.x; a1 += __int_as_float(q0.y) * v0.y;
        a0 += __int_as_float(q1.y) * v1.x; a1 += __int_as_float(q1.y) * v1.y;
        a0 += __int_as_float(q2.y) * v2.x; a1 += __int_as_float(q2.y) * v2.y;
        a0 += __int_as_float(q3.y) * v3.x; a1 += __int_as_float(q3.y) * v3.y;
    }
    for (; e < end; e += 64) {
        int2 r = csr[e];
        float w = __int_as_float(r.y);
        float2 gv = *(const float2*)(g2b + (((unsigned)r.x) >> 4));
        a0 += w * gv.x; a1 += w * gv.y;
    }
    #pragma unroll
    for (int off = 32; off > 0; off >>= 1) {
        a0 += __shfl_xor(a0, off, 64);
        a1 += __shfl_xor(a1, off, 64);
    }
    if (lane == 0) {
        float dv = dinv[wid];
        float2 sv = ((const float2*)g2)[wid];        // self-loop
        float z0 = dv * (a0 + sv.x) + b2[0];
        float z1 = dv * (a1 + sv.y) + b2[1];
        float m = fmaxf(z0, z1);
        float lse = m + logf(expf(z0 - m) + expf(z1 - m));
        ((float2*)out)[wid] = make_float2(z0 - lse, z1 - lse);
    }
}

extern "C" void kernel_launch(void* const* d_in, const int* in_sizes, int n_in,
                              void* d_out, int out_size, void* d_ws, size_t ws_size,
                              hipStream_t stream) {
    const float* x  = (const float*)d_in[0];
    const int*   ei = (const int*)d_in[1];    // [2, E]: src row then dst row
    const float* ew = (const float*)d_in[2];
    const float* W1 = (const float*)d_in[3];
    const float* b1 = (const float*)d_in[4];
    const float* W2 = (const float*)d_in[5];
    const float* b2 = (const float*)d_in[6];
    float* out = (float*)d_out;

    int n = in_sizes[0] / FIN;
    int E = in_sizes[2];
    const int* src = ei;
    const int* dst = ei + E;
    int NB = (n + BSZ - 1) / BSZ;             // 196 for n=100000 (<= MAXNB)
    int NCHUNK = (E + PCH - 1) / PCH;         // 391 for E=3.2M (<= 512 for k_scan_row)
    int M = NB * NCHUNK;

    // workspace carve-out, 16B-aligned
    char* ws = (char*)d_ws;
    size_t off = 0;
    auto alloc = [&](size_t bytes) -> void* {
        void* p = ws + off;
        off += (bytes + 15) & ~(size_t)15;
        return p;
    };
    int*    cmat    = (int*)   alloc((size_t)M * 4);      // 306 KB placement matrix
    int*    rsum    = (int*)   alloc((size_t)NB * 4);
    int*    bbase   = (int*)   alloc((size_t)NB * 4);
    int*    boff    = (int*)   alloc((size_t)(NB + 1) * 4);
    int*    row_ptr = (int*)   alloc((size_t)(n + 1) * 4);
    float*  dinv    = (float*) alloc((size_t)n * 4);
    int2*   recs_a  = (int2*)  alloc((size_t)E * 8);      // 25.6 MB (bucket order)
    int2*   recs_b  = (int2*)  alloc((size_t)E * 8);      // 25.6 MB (node order)
    __half* g1      = (__half*)alloc((size_t)n * F1 * 2); // 12.8 MB
    float*  g2      = (float*) alloc((size_t)n * 2 * 4);

    size_t place_lds = (size_t)PCH * 8 + (size_t)PCH * 4;    // lrec + addr32 = 96 KB
    size_t sort_lds  = (size_t)SCAP * 2;                     // inv16 = 48 KB

    k_hist     <<<NCHUNK, 256, 0, stream>>>(dst, cmat, E, NB, NCHUNK);
    k_scan_row <<<NB, 512, 0, stream>>>(cmat, rsum, NCHUNK);
    k_scan_buck<<<1, 1024, 0, stream>>>(rsum, bbase, boff, NB, E);
    k_place    <<<NCHUNK, 512, place_lds, stream>>>(src, dst, ew, cmat, bbase, recs_a, E, NB, NCHUNK);
    k_sort     <<<NB, 1024, sort_lds, stream>>>(boff, recs_a, recs_b, row_ptr, dinv, n);
    k_gemm1    <<<(n + 63) / 64, 256, 0, stream>>>(x, W1, dinv, g1, n);
    k_gather1  <<<(n + 3) / 4, 256, 0, stream>>>(row_ptr, recs_b, g1, dinv, b1, W2, g2, n);
    k_gather2  <<<(n + 3) / 4, 256, 0, stream>>>(row_ptr, recs_b, g2, dinv, b2, out, n);
}

// Round 16
// 297.304 us; speedup vs baseline: 1.0728x; 1.0728x over previous
//
#include <hip/hip_runtime.h>
#include <hip/hip_fp16.h>
#include <math.h>

#define FIN 35
#define F1  64
#define BSZ 256          // nodes per coarse bucket
#define BSH 8            // log2(BSZ)
#define GSH 7            // log2(g1 row bytes) = log2(64 feats * 2B)
#define MAXNB 512        // max buckets (n <= 131072)
#define PCH 8192         // edges per hist/place chunk => NCHUNK <= 512 for E <= 4.19M
#define SCAP 12288       // max bucket size for k_sort inv16 path (avg bucket ~8.2K)

// ---------- phase 1: per-chunk histogram of coarse buckets ----------
__global__ void k_hist(const int* __restrict__ dst, int* __restrict__ cmat,
                       int E, int NB, int NCHUNK) {
    __shared__ int h[MAXNB];
    int c = blockIdx.x, t = threadIdx.x;
    for (int i = t; i < NB; i += 256) h[i] = 0;
    __syncthreads();
    int e0 = c * PCH, e1 = min(e0 + PCH, E);
    bool al = ((size_t)(dst + e0) & 15) == 0;
    int nv = al ? ((e1 - e0) >> 2) : 0;
    const int4* d4 = (const int4*)(dst + e0);
    for (int i = t; i < nv; i += 256) {
        int4 v = d4[i];
        atomicAdd(&h[v.x >> BSH], 1); atomicAdd(&h[v.y >> BSH], 1);
        atomicAdd(&h[v.z >> BSH], 1); atomicAdd(&h[v.w >> BSH], 1);
    }
    for (int e = e0 + (nv << 2) + t; e < e1; e += 256) atomicAdd(&h[dst[e] >> BSH], 1);
    __syncthreads();
    for (int i = t; i < NB; i += 256) cmat[(size_t)i * NCHUNK + c] = h[i];  // b-major
}

// ---------- phase 2a: row-local exclusive scan (one block per bucket row; NCHUNK <= 512) ----------
__global__ void k_scan_row(int* __restrict__ cmat, int* __restrict__ rsum, int NCHUNK) {
    __shared__ int s[512];
    int b = blockIdx.x, t = threadIdx.x;
    int v = (t < NCHUNK) ? cmat[(size_t)b * NCHUNK + t] : 0;
    s[t] = v;
    __syncthreads();
    #pragma unroll
    for (int off = 1; off < 512; off <<= 1) {
        int tv = (t >= off) ? s[t - off] : 0;
        __syncthreads();
        s[t] += tv;
        __syncthreads();
    }
    if (t < NCHUNK) cmat[(size_t)b * NCHUNK + t] = s[t] - v;   // row-local exclusive
    if (t == 511) rsum[b] = s[511];                            // row total
}

// ---------- phase 2b: exclusive scan of row totals -> bucket bases + boff (NB <= 1024) ----------
__global__ void k_scan_buck(const int* __restrict__ rsum, int* __restrict__ bbase,
                            int* __restrict__ boff, int NB, int E) {
    __shared__ int s[1024];
    int t = threadIdx.x;
    int v = (t < NB) ? rsum[t] : 0;
    s[t] = v;
    __syncthreads();
    #pragma unroll
    for (int off = 1; off < 1024; off <<= 1) {
        int tv = (t >= off) ? s[t - off] : 0;
        __syncthreads();
        s[t] += tv;
        __syncthreads();
    }
    if (t < NB) {
        int excl = s[t] - v;
        bbase[t] = excl;
        boff[t] = excl;
    }
    if (t == 0) boff[NB] = E;
}

// ---------- phase 3: placement — chunk-local LDS counting sort -> coalesced output ----------
__global__ __launch_bounds__(512) void k_place(
        const int* __restrict__ src, const int* __restrict__ dst,
        const float* __restrict__ ew, const int* __restrict__ cmat,
        const int* __restrict__ bbase,
        int2* __restrict__ recs, int E, int NB, int NCHUNK) {
    extern __shared__ char pmem[];
    int2* lrec   = (int2*)pmem;              // PCH records (64 KB)
    int*  addr32 = (int*)(lrec + PCH);       // PCH global addresses (32 KB)
    __shared__ int s[512];                   // counts -> inclusive scan
    __shared__ int lbase[512];               // chunk-local bucket base
    __shared__ int cur[512];                 // chunk-local cursor
    __shared__ int gwin[512];                // global window base per bucket
    int c = blockIdx.x, t = threadIdx.x;
    s[t] = 0;
    __syncthreads();
    int e0 = c * PCH, e1 = min(e0 + PCH, E);
    bool al = (((size_t)(dst + e0) | (size_t)(src + e0) | (size_t)(ew + e0)) & 15) == 0;
    int nv = al ? ((e1 - e0) >> 2) : 0;
    const int4*   s4 = (const int4*)(src + e0);
    const int4*   d4 = (const int4*)(dst + e0);
    const float4* w4 = (const float4*)(ew + e0);
    // pass A: count
    for (int i = t; i < nv; i += 512) {
        int4 v = d4[i];
        atomicAdd(&s[v.x >> BSH], 1); atomicAdd(&s[v.y >> BSH], 1);
        atomicAdd(&s[v.z >> BSH], 1); atomicAdd(&s[v.w >> BSH], 1);
    }
    for (int e = e0 + (nv << 2) + t; e < e1; e += 512) atomicAdd(&s[dst[e] >> BSH], 1);
    __syncthreads();
    int v = s[t];
    __syncthreads();
    #pragma unroll
    for (int off = 1; off < 512; off <<= 1) {
        int tv = (t >= off) ? s[t - off] : 0;
        __syncthreads();
        s[t] += tv;
        __syncthreads();
    }
    lbase[t] = s[t] - v;
    cur[t] = 0;
    gwin[t] = (t < NB) ? (cmat[(size_t)t * NCHUNK + c] + bbase[t]) : 0;
    __syncthreads();
    // pass B: scatter into LDS (record + final global address)
    for (int i = t; i < nv; i += 512) {
        int4   sv = s4[i];
        int4   dv = d4[i];
        float4 wv = w4[i];
        int b, r, sl;
        b = dv.x >> BSH; r = atomicAdd(&cur[b], 1); sl = lbase[b] + r;
        lrec[sl] = make_int2(sv.x | ((dv.x & (BSZ-1)) << 24), __float_as_int(wv.x));
        addr32[sl] = gwin[b] + r;
        b = dv.y >> BSH; r = atomicAdd(&cur[b], 1); sl = lbase[b] + r;
        lrec[sl] = make_int2(sv.y | ((dv.y & (BSZ-1)) << 24), __float_as_int(wv.y));
        addr32[sl] = gwin[b] + r;
        b = dv.z >> BSH; r = atomicAdd(&cur[b], 1); sl = lbase[b] + r;
        lrec[sl] = make_int2(sv.z | ((dv.z & (BSZ-1)) << 24), __float_as_int(wv.z));
        addr32[sl] = gwin[b] + r;
        b = dv.w >> BSH; r = atomicAdd(&cur[b], 1); sl = lbase[b] + r;
        lrec[sl] = make_int2(sv.w | ((dv.w & (BSZ-1)) << 24), __float_as_int(wv.w));
        addr32[sl] = gwin[b] + r;
    }
    for (int e = e0 + (nv << 2) + t; e < e1; e += 512) {
        int d = dst[e];
        int b = d >> BSH;
        int r = atomicAdd(&cur[b], 1);
        int sl = lbase[b] + r;
        lrec[sl] = make_int2(src[e] | ((d & (BSZ-1)) << 24), __float_as_int(ew[e]));
        addr32[sl] = gwin[b] + r;
    }
    __syncthreads();
    // pass C: linear LDS walk -> coalesced bucket-major global stores
    int cnt = e1 - e0;
    for (int i = t; i < cnt; i += 512) recs[addr32[i]] = lrec[i];
}

// ---------- per-bucket counting sort via inverse permutation ----------
// 512 threads (8 waves) + 24KB LDS -> 4 blocks/CU: all 391 blocks co-resident
// in one occupancy round (no straggler tail). Records out carry src<<7.
__global__ __launch_bounds__(512) void k_sort(
        const int* __restrict__ boff, const int2* __restrict__ recs_in,
        int2* __restrict__ recs_out, int* __restrict__ row_ptr,
        float* __restrict__ dinv, int n) {
    extern __shared__ unsigned short inv16[];   // SCAP entries (24 KB)
    __shared__ int   hcnt[BSZ];
    __shared__ int   hoff[BSZ];
    __shared__ float dsum[BSZ];
    int b = blockIdx.x, t = threadIdx.x;
    if (t < BSZ) { hcnt[t] = 0; dsum[t] = 1.0f; }   // self-loop weight
    __syncthreads();
    int s0 = boff[b], s1 = boff[b + 1];
    int cnt = s1 - s0;
    // pass 1: histogram + weighted degree (coalesced global read)
    for (int i = t; i < cnt; i += 512) {
        int2 rc = recs_in[s0 + i];
        int dl = ((unsigned)rc.x) >> 24;
        atomicAdd(&hcnt[dl], 1);
        atomicAdd(&dsum[dl], __int_as_float(rc.y));
    }
    __syncthreads();
    int v = 0;
    if (t < BSZ) { v = hcnt[t]; hoff[t] = v; }
    __syncthreads();
    #pragma unroll
    for (int off = 1; off < BSZ; off <<= 1) {
        int tv = 0;
        if (t < BSZ && t >= off) tv = hoff[t - off];
        __syncthreads();
        if (t < BSZ) hoff[t] += tv;
        __syncthreads();
    }
    if (t < BSZ) {
        int excl = hoff[t] - v;
        int node = b * BSZ + t;
        if (node < n) {
            row_ptr[node] = s0 + excl;
            dinv[node] = rsqrtf(dsum[t]);
            if (node == n - 1) row_ptr[n] = s1;
        }
        hcnt[t] = excl;           // reuse as local cursor
    }
    __syncthreads();
    if (cnt <= SCAP) {
        // pass 2: positions -> inverse index (cnt <= SCAP < 65536 fits u16)
        for (int i = t; i < cnt; i += 512) {
            int2 rc = recs_in[s0 + i];
            int dl = ((unsigned)rc.x) >> 24;
            int pos = atomicAdd(&hcnt[dl], 1);
            inv16[pos] = (unsigned short)i;
        }
        __syncthreads();
        // pass 3: linear positions -> coalesced stores
        for (int o = t; o < cnt; o += 512) {
            int2 rc = recs_in[s0 + inv16[o]];
            recs_out[s0 + o] = make_int2((rc.x & 0xFFFFFF) << GSH, rc.y);
        }
    } else {
        // fallback (bucket larger than SCAP — not expected): direct scatter
        for (int i = t; i < cnt; i += 512) {
            int2 rc = recs_in[s0 + i];
            int dl = ((unsigned)rc.x) >> 24;
            int pos = atomicAdd(&hcnt[dl], 1);
            recs_out[s0 + pos] = make_int2((rc.x & 0xFFFFFF) << GSH, rc.y);
        }
    }
}

// ---------- layer 1 GEMM: 64 rows/block; float4-staged; g1 = fp16(dinv*x@W1) ----------
__global__ void k_gemm1(const float* __restrict__ x, const float* __restrict__ W1,
                        const float* __restrict__ dinv, __half* __restrict__ g1, int n) {
    __shared__ float W1s[FIN * F1];    // 8960 B
    __shared__ float xs[64 * FIN];     // 8960 B
    int t = threadIdx.x;
    // W1: 2240 floats, 16B-aligned -> 560 float4
    for (int i = t; i < (FIN * F1) / 4; i += 256) ((float4*)W1s)[i] = ((const float4*)W1)[i];
    int row0 = blockIdx.x * 64;
    int nrows = min(64, n - row0);
    // x slice starts at byte offset blockIdx*64*35*4 = blockIdx*8960 (16B-aligned)
    const float* xbase = x + (size_t)row0 * FIN;
    int tot = nrows * FIN;
    int totv = tot >> 2;
    for (int i = t; i < totv; i += 256) ((float4*)xs)[i] = ((const float4*)xbase)[i];
    for (int i = (totv << 2) + t; i < tot; i += 256) xs[i] = xbase[i];
    __syncthreads();
    int wave = t >> 6, f = t & 63;
    for (int rl = wave; rl < nrows; rl += 4) {
        float acc = 0.0f;
        #pragma unroll
        for (int k = 0; k < FIN; k++) acc += xs[rl * FIN + k] * W1s[k * F1 + f];
        int row = row0 + rl;
        g1[(size_t)row * F1 + f] = __float2half(acc * dinv[row]);
    }
}

// ---------- fused: layer-1 gather (fp16 rows, 16-way MLP, prescaled offsets)
// ---------- + ReLU + layer-2 GEMM (64->2) ----------
__global__ void k_gather1(const int* __restrict__ rp, const int2* __restrict__ csr,
                          const __half* __restrict__ g1,
                          const float* __restrict__ dinv, const float* __restrict__ b1,
                          const float* __restrict__ W2, float* __restrict__ g2, int n) {
    int wid = (int)((blockIdx.x * (long long)blockDim.x + threadIdx.x) >> 6);
    int f = threadIdx.x & 63;
    if (wid >= n) return;
    const char* g1b = (const char*)g1 + f * 2;   // lane's feature column
    int start = rp[wid], end = rp[wid + 1];
    float acc = 0.0f;
    int e = start;
    for (; e + 16 <= end; e += 16) {           // 16 row-gathers in flight
        float a[16];
        int2 r[16];
        #pragma unroll
        for (int j = 0; j < 16; j++) r[j] = csr[e + j];
        #pragma unroll
        for (int j = 0; j < 16; j++)
            a[j] = __half2float(*(const __half*)(g1b + (unsigned)r[j].x));
        #pragma unroll
        for (int j = 0; j < 16; j++) acc += __int_as_float(r[j].y) * a[j];
    }
    for (; e + 4 <= end; e += 4) {
        int2 r0 = csr[e], r1 = csr[e+1], r2 = csr[e+2], r3 = csr[e+3];
        float a0 = __half2float(*(const __half*)(g1b + (unsigned)r0.x));
        float a1 = __half2float(*(const __half*)(g1b + (unsigned)r1.x));
        float a2 = __half2float(*(const __half*)(g1b + (unsigned)r2.x));
        float a3 = __half2float(*(const __half*)(g1b + (unsigned)r3.x));
        acc += __int_as_float(r0.y) * a0; acc += __int_as_float(r1.y) * a1;
        acc += __int_as_float(r2.y) * a2; acc += __int_as_float(r3.y) * a3;
    }
    for (; e < end; e++) {
        int2 r = csr[e];
        acc += __int_as_float(r.y) * __half2float(*(const __half*)(g1b + (unsigned)r.x));
    }
    float dv = dinv[wid];
    float h = dv * (acc + __half2float(g1[(size_t)wid * F1 + f])) + b1[f]; // self-loop w=1
    h = h > 0.0f ? h : 0.0f;
    float2 w2v = ((const float2*)W2)[f];
    float z0 = h * w2v.x, z1 = h * w2v.y;
    #pragma unroll
    for (int off = 32; off > 0; off >>= 1) {
        z0 += __shfl_xor(z0, off, 64);
        z1 += __shfl_xor(z1, off, 64);
    }
    if (f == 0) {
        g2[(size_t)wid * 2 + 0] = dv * z0;
        g2[(size_t)wid * 2 + 1] = dv * z1;
    }
}

// ---------- fused: layer-2 gather (2 nodes/wave, 32 lanes each) + bias + log_softmax ----------
__global__ void k_gather2(const int* __restrict__ rp, const int2* __restrict__ csr,
                          const float* __restrict__ g2,
                          const float* __restrict__ dinv, const float* __restrict__ b2,
                          float* __restrict__ out, int n) {
    int w = (int)((blockIdx.x * (long long)blockDim.x + threadIdx.x) >> 6);
    int lane = threadIdx.x & 63;
    int half = lane >> 5, sub = lane & 31;
    int node = w * 2 + half;
    if (node >= n) return;                      // uniform within each 32-lane half
    const char* g2b = (const char*)g2;
    int start = rp[node], end = rp[node + 1];
    float a0 = 0.0f, a1 = 0.0f;
    int e = start + sub;
    for (; e + 96 < end; e += 128) {            // 4 gathers in flight, stride 32
        int2 q0 = csr[e], q1 = csr[e + 32], q2 = csr[e + 64], q3 = csr[e + 96];
        float2 v0 = *(const float2*)(g2b + (((unsigned)q0.x) >> 4));
        float2 v1 = *(const float2*)(g2b + (((unsigned)q1.x) >> 4));
        float2 v2 = *(const float2*)(g2b + (((unsigned)q2.x) >> 4));
        float2 v3 = *(const float2*)(g2b + (((unsigned)q3.x) >> 4));
        a0 += __int_as_float(q0.y) * v0.x; a1 += __int_as_float(q0.y) * v0.y;
        a0 += __int_as_float(q1.y) * v1.x; a1 += __int_as_float(q1.y) * v1.y;
        a0 += __int_as_float(q2.y) * v2.x; a1 += __int_as_float(q2.y) * v2.y;
        a0 += __int_as_float(q3.y) * v3.x; a1 += __int_as_float(q3.y) * v3.y;
    }
    for (; e < end; e += 32) {
        int2 r = csr[e];
        float wt = __int_as_float(r.y);
        float2 gv = *(const float2*)(g2b + (((unsigned)r.x) >> 4));
        a0 += wt * gv.x; a1 += wt * gv.y;
    }
    #pragma unroll
    for (int off = 16; off > 0; off >>= 1) {    // reduce within the 32-lane half
        a0 += __shfl_xor(a0, off, 64);
        a1 += __shfl_xor(a1, off, 64);
    }
    if (sub == 0) {
        float dv = dinv[node];
        float2 sv = ((const float2*)g2)[node];       // self-loop
        float z0 = dv * (a0 + sv.x) + b2[0];
        float z1 = dv * (a1 + sv.y) + b2[1];
        float m = fmaxf(z0, z1);
        float lse = m + logf(expf(z0 - m) + expf(z1 - m));
        ((float2*)out)[node] = make_float2(z0 - lse, z1 - lse);
    }
}

extern "C" void kernel_launch(void* const* d_in, const int* in_sizes, int n_in,
                              void* d_out, int out_size, void* d_ws, size_t ws_size,
                              hipStream_t stream) {
    const float* x  = (const float*)d_in[0];
    const int*   ei = (const int*)d_in[1];    // [2, E]: src row then dst row
    const float* ew = (const float*)d_in[2];
    const float* W1 = (const float*)d_in[3];
    const float* b1 = (const float*)d_in[4];
    const float* W2 = (const float*)d_in[5];
    const float* b2 = (const float*)d_in[6];
    float* out = (float*)d_out;

    int n = in_sizes[0] / FIN;
    int E = in_sizes[2];
    const int* src = ei;
    const int* dst = ei + E;
    int NB = (n + BSZ - 1) / BSZ;             // 391 for n=100000 (<= MAXNB)
    int NCHUNK = (E + PCH - 1) / PCH;         // 391 for E=3.2M (<= 512 for k_scan_row)
    int M = NB * NCHUNK;

    // workspace carve-out, 16B-aligned
    char* ws = (char*)d_ws;
    size_t off = 0;
    auto alloc = [&](size_t bytes) -> void* {
        void* p = ws + off;
        off += (bytes + 15) & ~(size_t)15;
        return p;
    };
    int*    cmat    = (int*)   alloc((size_t)M * 4);      // 612 KB placement matrix
    int*    rsum    = (int*)   alloc((size_t)NB * 4);
    int*    bbase   = (int*)   alloc((size_t)NB * 4);
    int*    boff    = (int*)   alloc((size_t)(NB + 1) * 4);
    int*    row_ptr = (int*)   alloc((size_t)(n + 1) * 4);
    float*  dinv    = (float*) alloc((size_t)n * 4);
    int2*   recs_a  = (int2*)  alloc((size_t)E * 8);      // 25.6 MB (bucket order)
    int2*   recs_b  = (int2*)  alloc((size_t)E * 8);      // 25.6 MB (node order)
    __half* g1      = (__half*)alloc((size_t)n * F1 * 2); // 12.8 MB
    float*  g2      = (float*) alloc((size_t)n * 2 * 4);

    size_t place_lds = (size_t)PCH * 8 + (size_t)PCH * 4;    // lrec + addr32 = 96 KB
    size_t sort_lds  = (size_t)SCAP * 2;                     // inv16 = 24 KB

    int g2_waves = (n + 1) / 2 + 1;           // 2 nodes per wave

    k_hist     <<<NCHUNK, 256, 0, stream>>>(dst, cmat, E, NB, NCHUNK);
    k_scan_row <<<NB, 512, 0, stream>>>(cmat, rsum, NCHUNK);
    k_scan_buck<<<1, 1024, 0, stream>>>(rsum, bbase, boff, NB, E);
    k_place    <<<NCHUNK, 512, place_lds, stream>>>(src, dst, ew, cmat, bbase, recs_a, E, NB, NCHUNK);
    k_sort     <<<NB, 512, sort_lds, stream>>>(boff, recs_a, recs_b, row_ptr, dinv, n);
    k_gemm1    <<<(n + 63) / 64, 256, 0, stream>>>(x, W1, dinv, g1, n);
    k_gather1  <<<(n + 3) / 4, 256, 0, stream>>>(row_ptr, recs_b, g1, dinv, b1, W2, g2, n);
    k_gather2  <<<(g2_waves + 3) / 4, 256, 0, stream>>>(row_ptr, recs_b, g2, dinv, b2, out, n);
}